// Round 7
// baseline (27.736 us; speedup 1.0000x reference)
//
#include <hip/hip_runtime.h>

#define GTCR_EPS 0.001f
#define GTCR_D 4096

// Kernel 1: 2048 blocks x 256 threads; one row per WAVE, waves fully
// autonomous (no LDS, no __syncthreads). Row = 1024 float4; lane reads
// 16 float4 (lane + 64k) in 4-deep batches (VGPR ~32 -> 8 blocks/CU).
// Wave shuffle-reduce -> lane 0 stores log1p(lmbd*||row||^2) to partial[row].
__global__ __launch_bounds__(256) void gtcr_row_kernel(
    const float* __restrict__ z, float* __restrict__ partial, float lmbd) {
    const int wid  = threadIdx.x >> 6;   // wave 0..3
    const int lane = threadIdx.x & 63;
    const int row  = blockIdx.x * 4 + wid;

    const float4* zr = reinterpret_cast<const float4*>(z) + (size_t)row * (GTCR_D / 4);

    float s0 = 0.0f, s1 = 0.0f, s2 = 0.0f, s3 = 0.0f;
    #pragma unroll
    for (int k = 0; k < 16; k += 4) {
        float4 v0 = zr[lane + 64 * (k + 0)];
        float4 v1 = zr[lane + 64 * (k + 1)];
        float4 v2 = zr[lane + 64 * (k + 2)];
        float4 v3 = zr[lane + 64 * (k + 3)];
        s0 = fmaf(v0.x, v0.x, fmaf(v0.y, v0.y, fmaf(v0.z, v0.z, fmaf(v0.w, v0.w, s0))));
        s1 = fmaf(v1.x, v1.x, fmaf(v1.y, v1.y, fmaf(v1.z, v1.z, fmaf(v1.w, v1.w, s1))));
        s2 = fmaf(v2.x, v2.x, fmaf(v2.y, v2.y, fmaf(v2.z, v2.z, fmaf(v2.w, v2.w, s2))));
        s3 = fmaf(v3.x, v3.x, fmaf(v3.y, v3.y, fmaf(v3.z, v3.z, fmaf(v3.w, v3.w, s3))));
    }
    float s = (s0 + s1) + (s2 + s3);

    // Wave-64 shuffle reduction: full row sum lands in lane 0.
    #pragma unroll
    for (int off = 32; off > 0; off >>= 1)
        s += __shfl_down(s, off, 64);

    if (lane == 0)
        partial[row] = log1pf(lmbd * s);
}

// Kernel 2: one 256-thread block reduces 8192 partials (2048 float4,
// 8 per thread, all issued up front).
__global__ __launch_bounds__(256) void gtcr_final_kernel(
    const float* __restrict__ partial, float* __restrict__ out, float scale) {
    const float4* p4 = reinterpret_cast<const float4*>(partial);

    float4 v[8];
    #pragma unroll
    for (int k = 0; k < 8; ++k)
        v[k] = p4[threadIdx.x + 256 * k];

    float s = 0.0f;
    #pragma unroll
    for (int k = 0; k < 8; ++k)
        s += ((v[k].x + v[k].y) + (v[k].z + v[k].w));

    #pragma unroll
    for (int off = 32; off > 0; off >>= 1)
        s += __shfl_down(s, off, 64);

    __shared__ float wsum[4];
    const int lane = threadIdx.x & 63;
    const int wid  = threadIdx.x >> 6;
    if (lane == 0) wsum[wid] = s;
    __syncthreads();
    if (threadIdx.x == 0) {
        float t = (wsum[0] + wsum[1]) + (wsum[2] + wsum[3]);
        out[0] = scale * t;   // scale = -0.5 / B
    }
}

extern "C" void kernel_launch(void* const* d_in, const int* in_sizes, int n_in,
                              void* d_out, int out_size, void* d_ws, size_t ws_size,
                              hipStream_t stream) {
    const float* z = (const float*)d_in[0];
    float* out = (float*)d_out;
    float* partial = (float*)d_ws;               // 8192 floats, fully overwritten

    const int B = in_sizes[0] / GTCR_D;          // 8192
    const int nblocks = B / 4;                   // 2048 = 8 blocks/CU
    const float lmbd = (float)GTCR_D * ((float)B * GTCR_EPS);  // 33554.432

    gtcr_row_kernel<<<nblocks, 256, 0, stream>>>(z, partial, lmbd);
    gtcr_final_kernel<<<1, 256, 0, stream>>>(partial, out, -0.5f / (float)B);
}

// Round 9
// 26.417 us; speedup vs baseline: 1.0499x; 1.0499x over previous
//
#include <hip/hip_runtime.h>

#define GTCR_EPS 0.001f
#define GTCR_D 4096

typedef float f4_t __attribute__((ext_vector_type(4)));  // native vector: OK for nontemporal builtin

// Kernel 1: 2048 blocks x 256 threads; one row per WAVE, waves autonomous
// (no LDS / no barrier). Row = 1024 float4; lane reads 16 float4
// (lane + 64k) in 4-deep batches via NONTEMPORAL loads (streaming read,
// zero reuse -> bypass cache allocation). Wave shuffle-reduce; lane 0
// stores log1p(lmbd*||row||^2) to partial[row].
__global__ __launch_bounds__(256) void gtcr_row_kernel(
    const float* __restrict__ z, float* __restrict__ partial, float lmbd) {
    const int wid  = threadIdx.x >> 6;   // wave 0..3
    const int lane = threadIdx.x & 63;
    const int row  = blockIdx.x * 4 + wid;

    const f4_t* zr = reinterpret_cast<const f4_t*>(z) + (size_t)row * (GTCR_D / 4);

    float s0 = 0.0f, s1 = 0.0f, s2 = 0.0f, s3 = 0.0f;
    #pragma unroll
    for (int k = 0; k < 16; k += 4) {
        f4_t v0 = __builtin_nontemporal_load(&zr[lane + 64 * (k + 0)]);
        f4_t v1 = __builtin_nontemporal_load(&zr[lane + 64 * (k + 1)]);
        f4_t v2 = __builtin_nontemporal_load(&zr[lane + 64 * (k + 2)]);
        f4_t v3 = __builtin_nontemporal_load(&zr[lane + 64 * (k + 3)]);
        s0 = fmaf(v0.x, v0.x, fmaf(v0.y, v0.y, fmaf(v0.z, v0.z, fmaf(v0.w, v0.w, s0))));
        s1 = fmaf(v1.x, v1.x, fmaf(v1.y, v1.y, fmaf(v1.z, v1.z, fmaf(v1.w, v1.w, s1))));
        s2 = fmaf(v2.x, v2.x, fmaf(v2.y, v2.y, fmaf(v2.z, v2.z, fmaf(v2.w, v2.w, s2))));
        s3 = fmaf(v3.x, v3.x, fmaf(v3.y, v3.y, fmaf(v3.z, v3.z, fmaf(v3.w, v3.w, s3))));
    }
    float s = (s0 + s1) + (s2 + s3);

    // Wave-64 shuffle reduction: full row sum lands in lane 0.
    #pragma unroll
    for (int off = 32; off > 0; off >>= 1)
        s += __shfl_down(s, off, 64);

    if (lane == 0)
        partial[row] = log1pf(lmbd * s);
}

// Kernel 2: one 256-thread block reduces 8192 partials (2048 float4,
// 8 per thread, all issued up front).
__global__ __launch_bounds__(256) void gtcr_final_kernel(
    const float* __restrict__ partial, float* __restrict__ out, float scale) {
    const f4_t* p4 = reinterpret_cast<const f4_t*>(partial);

    f4_t v[8];
    #pragma unroll
    for (int k = 0; k < 8; ++k)
        v[k] = p4[threadIdx.x + 256 * k];

    float s = 0.0f;
    #pragma unroll
    for (int k = 0; k < 8; ++k)
        s += ((v[k].x + v[k].y) + (v[k].z + v[k].w));

    #pragma unroll
    for (int off = 32; off > 0; off >>= 1)
        s += __shfl_down(s, off, 64);

    __shared__ float wsum[4];
    const int lane = threadIdx.x & 63;
    const int wid  = threadIdx.x >> 6;
    if (lane == 0) wsum[wid] = s;
    __syncthreads();
    if (threadIdx.x == 0) {
        float t = (wsum[0] + wsum[1]) + (wsum[2] + wsum[3]);
        out[0] = scale * t;   // scale = -0.5 / B
    }
}

extern "C" void kernel_launch(void* const* d_in, const int* in_sizes, int n_in,
                              void* d_out, int out_size, void* d_ws, size_t ws_size,
                              hipStream_t stream) {
    const float* z = (const float*)d_in[0];
    float* out = (float*)d_out;
    float* partial = (float*)d_ws;               // 8192 floats, fully overwritten

    const int B = in_sizes[0] / GTCR_D;          // 8192
    const int nblocks = B / 4;                   // 2048 = 8 blocks/CU
    const float lmbd = (float)GTCR_D * ((float)B * GTCR_EPS);  // 33554.432

    gtcr_row_kernel<<<nblocks, 256, 0, stream>>>(z, partial, lmbd);
    gtcr_final_kernel<<<1, 256, 0, stream>>>(partial, out, -0.5f / (float)B);
}